// Round 7
// baseline (96.201 us; speedup 1.0000x reference)
//
#include <hip/hip_runtime.h>
#include <hip/hip_fp16.h>

typedef _Float16 half8 __attribute__((ext_vector_type(8)));
typedef __fp16 cvt2_t __attribute__((ext_vector_type(2)));
typedef float f32x4 __attribute__((ext_vector_type(4)));

// ---------------- workspace layout (bytes) ----------------
// W0F: fragment-ordered w0 fp16: linear uint4 index = t*1024 + kf*512 + nf*64 + l
//      element e of lane l = w0[n=nf*16+(l&15)][k=t*64+kf*32+(l>>4)*8+e], zero-padded
#define W0F_UNITS (13 * 1024)              // uint4 units
#define W1F_OFF   (W0F_UNITS * 16)         // 212992
#define W1F_UNITS 512                      // kf*128 + nf*64 + l
#define SW_OFF    (W1F_OFF + W1F_UNITS * 16)  // 221184
// SW (fp32): w3[22*32] @0 | w5p[21][24] @2816B | w7p[10][24] @4832B | b3 @5792B | b5 @5888B

// ---------------- LDS (per 1-wave block) ----------------
#define L_H0   0        // [32 r][128 c] half, byte = r*256 + (2c ^ ((r&7)<<4))  (8192 B)
#define L_H1   8192     // [32 r][32 c]  half, byte = r*64  + (2c ^ ((r&3)<<4))  (2048 B)
#define L_H3   0        // [32][25] f32 (3200 B)  -- overlays H0 after main loop
#define L_H5   3200     // [32][25] f32 (3200 B)
#define L_OS   6400     // [320] f32 out staging (1280 B)
#define LDS_SZ 10240

// ============ prep: rearrange weights into fragment order ============
__global__ void prep_weights(const float* __restrict__ w0,
                             const float* __restrict__ w1,
                             const float* __restrict__ w3,
                             const float* __restrict__ b3,
                             const float* __restrict__ w5,
                             const float* __restrict__ b5,
                             const float* __restrict__ w7,
                             char* __restrict__ ws) {
  int tid = blockIdx.x * 256 + threadIdx.x;
  if (tid < W0F_UNITS) {
    int t  = tid >> 10;
    int kf = (tid >> 9) & 1;
    int nf = (tid >> 6) & 7;
    int l  = tid & 63;
    int n  = nf * 16 + (l & 15);
    int k0 = t * 64 + kf * 32 + (l >> 4) * 8;
    alignas(16) __half h[8];
#pragma unroll
    for (int e = 0; e < 8; e++) {
      int k = k0 + e;
      h[e] = __float2half((n < 124 && k < 784) ? w0[n * 784 + k] : 0.f);
    }
    *(uint4*)(ws + tid * 16) = *(const uint4*)h;
    return;
  }
  int r = tid - W0F_UNITS;
  if (r < W1F_UNITS) {
    int kf = r >> 7;
    int nf = (r >> 6) & 1;
    int l  = r & 63;
    int n  = nf * 16 + (l & 15);
    int k0 = kf * 32 + (l >> 4) * 8;
    alignas(16) __half h[8];
#pragma unroll
    for (int e = 0; e < 8; e++) {
      int k = k0 + e;
      h[e] = __float2half((k < 124) ? w1[n * 124 + k] : 0.f);
    }
    *(uint4*)(ws + W1F_OFF + r * 16) = *(const uint4*)h;
    return;
  }
  r -= W1F_UNITS;
  float* sw = (float*)(ws + SW_OFF);
  if (r < 704) { sw[r] = w3[r]; return; }                     // w3 [22][32]
  r -= 704;
  if (r < 504) {                                              // w5 [21][24]
    int n = r / 24, k = r % 24;
    sw[704 + r] = (k < 22) ? w5[n * 22 + k] : 0.f;
    return;
  }
  r -= 504;
  if (r < 240) {                                              // w7 [10][24]
    int n = r / 24, k = r % 24;
    sw[1208 + r] = (k < 21) ? w7[n * 21 + k] : 0.f;
    return;
  }
  r -= 240;
  if (r < 24) { sw[1448 + r] = (r < 22) ? b3[r] : 0.f; return; }
  r -= 24;
  if (r < 24) { sw[1472 + r] = (r < 21) ? b5[r] : 0.f; return; }
}

// ============ fused MLP: 1 wave = 32 rows, no barriers, depth-2 x pipeline ====
__device__ __forceinline__ half8 cvt8(const f32x4& a, const f32x4& b) {
  cvt2_t p0 = __builtin_amdgcn_cvt_pkrtz(a[0], a[1]);
  cvt2_t p1 = __builtin_amdgcn_cvt_pkrtz(a[2], a[3]);
  cvt2_t p2 = __builtin_amdgcn_cvt_pkrtz(b[0], b[1]);
  cvt2_t p3 = __builtin_amdgcn_cvt_pkrtz(b[2], b[3]);
  uint4 u;
  u.x = __builtin_bit_cast(unsigned, p0);
  u.y = __builtin_bit_cast(unsigned, p1);
  u.z = __builtin_bit_cast(unsigned, p2);
  u.w = __builtin_bit_cast(unsigned, p3);
  return __builtin_bit_cast(half8, u);
}

__global__ __launch_bounds__(64, 2) void fused_mlp(
    const float* __restrict__ x, const char* __restrict__ ws,
    float* __restrict__ out) {
  __shared__ alignas(16) char sm[LDS_SZ];
  const int l  = threadIdx.x;
  const int lr = l & 15;
  const int lg = l >> 4;
  const size_t row0 = (size_t)blockIdx.x * 32;

  const float* xb0 = x + (row0 + lr) * 784;
  const float* xb1 = xb0 + 16 * 784;

  f32x4 acc[2][8];
#pragma unroll
  for (int mf = 0; mf < 2; mf++)
#pragma unroll
    for (int nf = 0; nf < 8; nf++) acc[mf][nf] = f32x4{0.f, 0.f, 0.f, 0.f};

  const uint4* wf = (const uint4*)ws;

  f32x4 xP[2][2][2], xQ[2][2][2];   // [mf][kf][h] raw fp32, ping-pong depth-2
  half8 bfr[2][8];

  // nontemporal load of tile T into buffer B (x is a 205 MB stream read once:
  // keep it OUT of L2 so the w0 fragment set stays resident).
  // G=1: partial tile 12 (only kf==0 && lg<2 valid)
#define XLOAD(T, B, G)                                                         \
  {                                                                            \
    _Pragma("unroll") for (int mf = 0; mf < 2; mf++)                           \
        _Pragma("unroll") for (int kf = 0; kf < 2; kf++) {                     \
      const float* p = (mf ? xb1 : xb0) + (T) * 64 + kf * 32 + lg * 8;         \
      if (!(G) || (kf == 0 && lg < 2)) {                                       \
        B[mf][kf][0] = __builtin_nontemporal_load((const f32x4*)p);            \
        B[mf][kf][1] = __builtin_nontemporal_load((const f32x4*)(p + 4));      \
      } else {                                                                 \
        B[mf][kf][0] = f32x4{0.f, 0.f, 0.f, 0.f};                              \
        B[mf][kf][1] = f32x4{0.f, 0.f, 0.f, 0.f};                              \
      }                                                                        \
    }                                                                          \
  }

#define BF(T)                                                                  \
  _Pragma("unroll") for (int kf = 0; kf < 2; kf++)                             \
      _Pragma("unroll") for (int nf = 0; nf < 8; nf++)                         \
          bfr[kf][nf] = __builtin_bit_cast(                                    \
              half8, wf[(T) * 1024 + kf * 512 + nf * 64 + l]);

  // cvt(T) then MFMA(T). Waits: cvt -> x(T) (2-body slack); MFMA -> bf(T)
  // (1-body slack); both waits keep the younger x-prefetch in flight.
#define BODY(B)                                                                \
  {                                                                            \
    half8 af[2][2];                                                            \
    _Pragma("unroll") for (int mf = 0; mf < 2; mf++)                           \
        _Pragma("unroll") for (int kf = 0; kf < 2; kf++)                       \
            af[mf][kf] = cvt8(B[mf][kf][0], B[mf][kf][1]);                     \
    _Pragma("unroll") for (int kf = 0; kf < 2; kf++)                           \
        _Pragma("unroll") for (int mf = 0; mf < 2; mf++)                       \
            _Pragma("unroll") for (int nf = 0; nf < 8; nf++)                   \
                acc[mf][nf] = __builtin_amdgcn_mfma_f32_16x16x32_f16(          \
                    af[mf][kf], bfr[kf][nf], acc[mf][nf], 0, 0, 0);            \
  }

  // prologue: x(0), bf(0), x(1) — bf(0) issued before x(1) so its wait
  // keeps x(1) in flight.
  XLOAD(0, xP, 0)
  BF(0)
  XLOAD(1, xQ, 0)

  BODY(xP) BF(1)  XLOAD(2, xP, 0)
  BODY(xQ) BF(2)  XLOAD(3, xQ, 0)
  BODY(xP) BF(3)  XLOAD(4, xP, 0)
  BODY(xQ) BF(4)  XLOAD(5, xQ, 0)
  BODY(xP) BF(5)  XLOAD(6, xP, 0)
  BODY(xQ) BF(6)  XLOAD(7, xQ, 0)
  BODY(xP) BF(7)  XLOAD(8, xP, 0)
  BODY(xQ) BF(8)  XLOAD(9, xQ, 0)
  BODY(xP) BF(9)  XLOAD(10, xP, 0)
  BODY(xQ) BF(10) XLOAD(11, xQ, 0)
  BODY(xP) BF(11) XLOAD(12, xP, 1)   // tile 12 partial, zero-filled
  BODY(xQ) BF(12)
  BODY(xP)                            // tile 12 (zeros beyond k=784)

  // issue w1 fragment loads early (consumed in phase 2, hides L2 latency)
  half8 b1[4][2];
  {
    const uint4* w1f = (const uint4*)(ws + W1F_OFF);
#pragma unroll
    for (int kf = 0; kf < 4; kf++)
#pragma unroll
      for (int nf = 0; nf < 2; nf++)
        b1[kf][nf] = __builtin_bit_cast(half8, w1f[kf * 128 + nf * 64 + l]);
  }

  // ---- phase 1: h0 (fp32 acc, no activation) -> LDS fp16, swizzled ----
#pragma unroll
  for (int mf = 0; mf < 2; mf++)
#pragma unroll
    for (int nf = 0; nf < 8; nf++)
#pragma unroll
      for (int q = 0; q < 4; q++) {
        int rr = mf * 16 + lg * 4 + q;
        int cc = nf * 16 + lr;
        *(__half*)(sm + L_H0 + rr * 256 + ((2 * cc) ^ ((rr & 7) << 4))) =
            __float2half(acc[mf][nf][q]);
      }
  __syncthreads();   // 1-wave block: cheap

  // ---- phase 2: layer 1 (N=32, K=128pad) + relu -> h1 ----
  f32x4 acc1[2][2];
#pragma unroll
  for (int mf = 0; mf < 2; mf++) {
    acc1[mf][0] = f32x4{0.f, 0.f, 0.f, 0.f};
    acc1[mf][1] = f32x4{0.f, 0.f, 0.f, 0.f};
  }
#pragma unroll
  for (int kf = 0; kf < 4; kf++) {
    half8 a1[2];
#pragma unroll
    for (int mf = 0; mf < 2; mf++) {
      int rr = mf * 16 + lr;
      int cb = kf * 64 + lg * 16;   // byte offset of k-group
      a1[mf] = *(const half8*)(sm + L_H0 + rr * 256 + (cb ^ ((rr & 7) << 4)));
    }
#pragma unroll
    for (int mf = 0; mf < 2; mf++)
#pragma unroll
      for (int nf = 0; nf < 2; nf++)
        acc1[mf][nf] = __builtin_amdgcn_mfma_f32_16x16x32_f16(
            a1[mf], b1[kf][nf], acc1[mf][nf], 0, 0, 0);
  }
#pragma unroll
  for (int mf = 0; mf < 2; mf++)
#pragma unroll
    for (int nf = 0; nf < 2; nf++)
#pragma unroll
      for (int q = 0; q < 4; q++) {
        int rr = mf * 16 + lg * 4 + q;
        int cc = nf * 16 + lr;
        float v = fmaxf(acc1[mf][nf][q], 0.f);
        *(__half*)(sm + L_H1 + rr * 64 + ((2 * cc) ^ ((rr & 3) << 4))) =
            __float2half(v);
      }
  __syncthreads();

  // ---- phase 3: layers 3,5,7 + log_softmax (fp32, 2 lanes per row) ----
  const int r = l & 31;
  const int j = l >> 5;
  float h1v[32];
#pragma unroll
  for (int cb = 0; cb < 4; cb++) {
    half8 v = *(const half8*)(sm + L_H1 + r * 64 + ((cb * 16) ^ ((r & 3) << 4)));
#pragma unroll
    for (int e = 0; e < 8; e++) h1v[cb * 8 + e] = (float)v[e];
  }
  const float* w3g = (const float*)(ws + SW_OFF);
  const float* w5g = (const float*)(ws + SW_OFF + 2816);
  const float* w7g = (const float*)(ws + SW_OFF + 4832);
  const float* b3g = (const float*)(ws + SW_OFF + 5792);
  const float* b5g = (const float*)(ws + SW_OFF + 5888);
  float* h3l = (float*)(sm + L_H3);
  float* h5l = (float*)(sm + L_H5);

#pragma unroll
  for (int i = 0; i < 11; i++) {
    int n = j + 2 * i;
    float s = b3g[n];
    const float4* wrow = (const float4*)(w3g + n * 32);
#pragma unroll
    for (int kk = 0; kk < 8; kk++) {
      float4 wv = wrow[kk];
      s += h1v[4 * kk] * wv.x + h1v[4 * kk + 1] * wv.y +
           h1v[4 * kk + 2] * wv.z + h1v[4 * kk + 3] * wv.w;
    }
    h3l[r * 25 + n] = fmaxf(s, 0.f);
  }
  __syncthreads();
  float h3v[24];
#pragma unroll
  for (int k = 0; k < 24; k++) h3v[k] = (k < 22) ? h3l[r * 25 + k] : 0.f;
#pragma unroll
  for (int i = 0; i < 11; i++) {
    int n = j + 2 * i;
    if (n < 21) {
      float s = b5g[n];
      const float4* wrow = (const float4*)(w5g + n * 24);
#pragma unroll
      for (int kk = 0; kk < 6; kk++) {
        float4 wv = wrow[kk];
        s += h3v[4 * kk] * wv.x + h3v[4 * kk + 1] * wv.y +
             h3v[4 * kk + 2] * wv.z + h3v[4 * kk + 3] * wv.w;
      }
      h5l[r * 25 + n] = fmaxf(s, 0.f);
    }
  }
  __syncthreads();
  if (j == 0) {
    float h5v[24];
#pragma unroll
    for (int k = 0; k < 24; k++) h5v[k] = (k < 21) ? h5l[r * 25 + k] : 0.f;
    float lgt[10];
    float mx = -3.4e38f;
#pragma unroll
    for (int n = 0; n < 10; n++) {
      float s = 0.f;
      const float4* wrow = (const float4*)(w7g + n * 24);
#pragma unroll
      for (int kk = 0; kk < 6; kk++) {
        float4 wv = wrow[kk];
        s += h5v[4 * kk] * wv.x + h5v[4 * kk + 1] * wv.y +
             h5v[4 * kk + 2] * wv.z + h5v[4 * kk + 3] * wv.w;
      }
      lgt[n] = s;
      mx = fmaxf(mx, s);
    }
    float se = 0.f;
#pragma unroll
    for (int n = 0; n < 10; n++) se += __expf(lgt[n] - mx);
    const float lse = mx + __logf(se);
    float* os = (float*)(sm + L_OS);
#pragma unroll
    for (int n = 0; n < 10; n++) os[r * 10 + n] = lgt[n] - lse;
  }
  __syncthreads();
  {
    const float* os = (const float*)(sm + L_OS);
#pragma unroll
    for (int i = 0; i < 5; i++)
      __builtin_nontemporal_store(os[i * 64 + l], &out[row0 * 10 + i * 64 + l]);
  }
}

extern "C" void kernel_launch(void* const* d_in, const int* in_sizes, int n_in,
                              void* d_out, int out_size, void* d_ws, size_t ws_size,
                              hipStream_t stream) {
  const float* x  = (const float*)d_in[0];
  const float* w0 = (const float*)d_in[1];
  const float* w1 = (const float*)d_in[2];
  const float* w3 = (const float*)d_in[3];
  const float* b3 = (const float*)d_in[4];
  const float* w5 = (const float*)d_in[5];
  const float* b5 = (const float*)d_in[6];
  const float* w7 = (const float*)d_in[7];
  float* out = (float*)d_out;
  char* ws = (char*)d_ws;

  const int prep_threads = W0F_UNITS + W1F_UNITS + 704 + 504 + 240 + 24 + 24;
  prep_weights<<<(prep_threads + 255) / 256, 256, 0, stream>>>(w0, w1, w3, b3,
                                                               w5, b5, w7, ws);
  fused_mlp<<<65536 / 32, 64, 0, stream>>>(x, ws, out);
}

// Round 8
// 74.738 us; speedup vs baseline: 1.2872x; 1.2872x over previous
//
#include <hip/hip_runtime.h>
#include <hip/hip_fp16.h>

typedef _Float16 half8 __attribute__((ext_vector_type(8)));
typedef __fp16 cvt2_t __attribute__((ext_vector_type(2)));
typedef float f32x4 __attribute__((ext_vector_type(4)));

// ---------------- workspace layout (bytes) ----------------
// W0F: fragment-ordered w0 fp16: uint4 index = t*1024 + kf*512 + nf*64 + l
//      (t = k/64 tile, kf = k32-half). Global k32-frag g -> t=g>>1, kf=g&1.
#define W0F_UNITS (13 * 1024)
#define W1F_OFF   (W0F_UNITS * 16)
#define W1F_UNITS 512
#define SW_OFF    (W1F_OFF + W1F_UNITS * 16)

// ---------------- LDS (per 1-wave block, 16 rows) ----------------
#define L_XT   0        // [16 r][256 c] fp16, byte = r*512 + ((2c)^((r&7)<<4))  (8192)
#define L_H0   0        // [16][128] fp16, r*256 + ((2c)^((r&7)<<4)) (4096, overlays XT)
#define L_H1   4096     // [16][32] fp16, r*64 + ((2c)^((r&3)<<4)) (1024)
#define L_H3   5120     // [16][25] f32 (1600)
#define L_H5   6720     // [16][25] f32 (1600)
#define L_OS   8320     // [160] f32 (640)
#define LDS_SZ 10240

// ============ prep: rearrange weights into fragment order (unchanged) ============
__global__ void prep_weights(const float* __restrict__ w0,
                             const float* __restrict__ w1,
                             const float* __restrict__ w3,
                             const float* __restrict__ b3,
                             const float* __restrict__ w5,
                             const float* __restrict__ b5,
                             const float* __restrict__ w7,
                             char* __restrict__ ws) {
  int tid = blockIdx.x * 256 + threadIdx.x;
  if (tid < W0F_UNITS) {
    int t  = tid >> 10;
    int kf = (tid >> 9) & 1;
    int nf = (tid >> 6) & 7;
    int l  = tid & 63;
    int n  = nf * 16 + (l & 15);
    int k0 = t * 64 + kf * 32 + (l >> 4) * 8;
    alignas(16) __half h[8];
#pragma unroll
    for (int e = 0; e < 8; e++) {
      int k = k0 + e;
      h[e] = __float2half((n < 124 && k < 784) ? w0[n * 784 + k] : 0.f);
    }
    *(uint4*)(ws + tid * 16) = *(const uint4*)h;
    return;
  }
  int r = tid - W0F_UNITS;
  if (r < W1F_UNITS) {
    int kf = r >> 7;
    int nf = (r >> 6) & 1;
    int l  = r & 63;
    int n  = nf * 16 + (l & 15);
    int k0 = kf * 32 + (l >> 4) * 8;
    alignas(16) __half h[8];
#pragma unroll
    for (int e = 0; e < 8; e++) {
      int k = k0 + e;
      h[e] = __float2half((k < 124) ? w1[n * 124 + k] : 0.f);
    }
    *(uint4*)(ws + W1F_OFF + r * 16) = *(const uint4*)h;
    return;
  }
  r -= W1F_UNITS;
  float* sw = (float*)(ws + SW_OFF);
  if (r < 704) { sw[r] = w3[r]; return; }
  r -= 704;
  if (r < 504) {
    int n = r / 24, k = r % 24;
    sw[704 + r] = (k < 22) ? w5[n * 22 + k] : 0.f;
    return;
  }
  r -= 504;
  if (r < 240) {
    int n = r / 24, k = r % 24;
    sw[1208 + r] = (k < 21) ? w7[n * 21 + k] : 0.f;
    return;
  }
  r -= 240;
  if (r < 24) { sw[1448 + r] = (r < 22) ? b3[r] : 0.f; return; }
  r -= 24;
  if (r < 24) { sw[1472 + r] = (r < 21) ? b5[r] : 0.f; return; }
}

// ============ fused MLP: 1 wave = 16 rows, K-tile = 256 (1 KB/row reads) ============
__global__ __launch_bounds__(64, 2) void fused_mlp(
    const float* __restrict__ x, const char* __restrict__ ws,
    float* __restrict__ out) {
  __shared__ alignas(16) char sm[LDS_SZ];
  const int l  = threadIdx.x;
  const int lr = l & 15;
  const int lg = l >> 4;
  const size_t row0 = (size_t)blockIdx.x * 16;
  const uint4* wf = (const uint4*)ws;

  f32x4 acc[8];
#pragma unroll
  for (int nf = 0; nf < 8; nf++) acc[nf] = f32x4{0.f, 0.f, 0.f, 0.f};

  f32x4 xg0[8], xg1[8];   // row-group staging (rows 0-7, 8-15), 1 KB/row loads
  half8 bfr[2][8];        // bf ping-pong by kf parity
  half8 af[8];            // A-fragments of current tile (preloaded from LDS)

  // contiguous 1 KB row load: lane l takes floats [4l,4l+4) of the row
#define XLOADG(T, XG, RB, GUARD)                                               \
  {                                                                            \
    _Pragma("unroll") for (int i = 0; i < 8; i++) {                            \
      const float* p = x + (row0 + (RB) + i) * 784 + (T) * 256 + 4 * l;        \
      XG[i] = (!(GUARD) || l < 4) ? *(const f32x4*)p                           \
                                  : f32x4{0.f, 0.f, 0.f, 0.f};                 \
    }                                                                          \
  }

  // cvt fp32->fp16, swizzled LDS store (8 B/lane/row)
#define XSTOREG(XG, RB)                                                        \
  {                                                                            \
    _Pragma("unroll") for (int i = 0; i < 8; i++) {                            \
      cvt2_t q0 = __builtin_amdgcn_cvt_pkrtz(XG[i][0], XG[i][1]);              \
      cvt2_t q1 = __builtin_amdgcn_cvt_pkrtz(XG[i][2], XG[i][3]);              \
      uint2 u;                                                                 \
      u.x = __builtin_bit_cast(unsigned, q0);                                  \
      u.y = __builtin_bit_cast(unsigned, q1);                                  \
      *(uint2*)(sm + L_XT + ((RB) + i) * 512 +                                 \
                ((8 * l) ^ ((((RB) + i) & 7) << 4))) = u;                      \
    }                                                                          \
  }

#define AREAD1(KF)                                                             \
  af[KF] = *(const half8*)(sm + L_XT + lr * 512 +                              \
                           (((KF) * 64 + lg * 16) ^ ((lr & 7) << 4)));

#define AREAD_ALL()                                                            \
  { _Pragma("unroll") for (int kf = 0; kf < 8; kf++) AREAD1(kf) }

#define BFL(P, G)                                                              \
  {                                                                            \
    _Pragma("unroll") for (int nf = 0; nf < 8; nf++)                           \
      bfr[P][nf] = __builtin_bit_cast(                                         \
          half8, wf[((G) >> 1) * 1024 + ((G) & 1) * 512 + nf * 64 + l]);       \
  }

#define MF(KF, P)                                                              \
  {                                                                            \
    _Pragma("unroll") for (int nf = 0; nf < 8; nf++)                           \
      acc[nf] = __builtin_amdgcn_mfma_f32_16x16x32_f16(af[KF], bfr[P][nf],     \
                                                       acc[nf], 0, 0, 0);      \
  }

  // body: compute tile T (8 k-frags) from LDS, stage tile T+1 (x in regs ->
  // LDS at end). bf issue order keeps the x prefetch in flight through kf0/kf1.
#define BODY(T, STAGE, GUARD)                                                  \
  {                                                                            \
    AREAD_ALL()                                                                \
    BFL(0, (T) * 8 + 0)                                                        \
    BFL(1, (T) * 8 + 1)                                                        \
    if (STAGE) {                                                               \
      XLOADG((T) + 1, xg0, 0, GUARD)                                           \
      XLOADG((T) + 1, xg1, 8, GUARD)                                           \
    }                                                                          \
    MF(0, 0)                                                                   \
    BFL(0, (T) * 8 + 2)                                                        \
    MF(1, 1)                                                                   \
    BFL(1, (T) * 8 + 3)                                                        \
    MF(2, 0)                                                                   \
    BFL(0, (T) * 8 + 4)                                                        \
    MF(3, 1)                                                                   \
    BFL(1, (T) * 8 + 5)                                                        \
    MF(4, 0)                                                                   \
    BFL(0, (T) * 8 + 6)                                                        \
    MF(5, 1)                                                                   \
    BFL(1, (T) * 8 + 7)                                                        \
    MF(6, 0)                                                                   \
    MF(7, 1)                                                                   \
    if (STAGE) {                                                               \
      XSTOREG(xg0, 0)                                                          \
      XSTOREG(xg1, 8)                                                          \
    }                                                                          \
  }

  // prologue: stage tile 0
  XLOADG(0, xg0, 0, 0)
  XLOADG(0, xg1, 8, 0)
  XSTOREG(xg0, 0)
  XSTOREG(xg1, 8)

  BODY(0, 1, 0)   // compute tile 0, stage tile 1
  BODY(1, 1, 0)   // compute tile 1, stage tile 2
  BODY(2, 1, 1)   // compute tile 2, stage tile 3 (partial: l<4 valid)

  // tile 3: k 768..832 (2 k-frags, zero-padded beyond 784)
  AREAD1(0)
  AREAD1(1)
  BFL(0, 24)
  BFL(1, 25)
  MF(0, 0)
  MF(1, 1)

  // issue w1 fragment loads early (consumed in phase 2)
  half8 b1[4][2];
  {
    const uint4* w1f = (const uint4*)(ws + W1F_OFF);
#pragma unroll
    for (int kf = 0; kf < 4; kf++)
#pragma unroll
      for (int nf = 0; nf < 2; nf++)
        b1[kf][nf] = __builtin_bit_cast(half8, w1f[kf * 128 + nf * 64 + l]);
  }

  // ---- phase 1: h0 -> LDS fp16 (overlays XT) ----
#pragma unroll
  for (int nf = 0; nf < 8; nf++)
#pragma unroll
    for (int q = 0; q < 4; q++) {
      int rr = lg * 4 + q;
      int cc = nf * 16 + lr;
      *(__half*)(sm + L_H0 + rr * 256 + ((2 * cc) ^ ((rr & 7) << 4))) =
          __float2half(acc[nf][q]);
    }
  __syncthreads();

  // ---- phase 2: layer 1 (N=32, K=128pad) + relu -> h1 ----
  f32x4 acc1[2];
  acc1[0] = f32x4{0.f, 0.f, 0.f, 0.f};
  acc1[1] = f32x4{0.f, 0.f, 0.f, 0.f};
#pragma unroll
  for (int kf = 0; kf < 4; kf++) {
    int cb = kf * 64 + lg * 16;
    half8 a1 = *(const half8*)(sm + L_H0 + lr * 256 + (cb ^ ((lr & 7) << 4)));
#pragma unroll
    for (int nf = 0; nf < 2; nf++)
      acc1[nf] = __builtin_amdgcn_mfma_f32_16x16x32_f16(a1, b1[kf][nf],
                                                        acc1[nf], 0, 0, 0);
  }
#pragma unroll
  for (int nf = 0; nf < 2; nf++)
#pragma unroll
    for (int q = 0; q < 4; q++) {
      int rr = lg * 4 + q;
      int cc = nf * 16 + lr;
      float v = fmaxf(acc1[nf][q], 0.f);
      *(__half*)(sm + L_H1 + rr * 64 + ((2 * cc) ^ ((rr & 3) << 4))) =
          __float2half(v);
    }
  __syncthreads();

  // ---- phase 3: layers 3,5,7 + log_softmax (fp32, 4 lanes per row) ----
  const int r = l & 15;
  const int j = l >> 4;   // 0..3
  float h1v[32];
#pragma unroll
  for (int cb = 0; cb < 4; cb++) {
    half8 v = *(const half8*)(sm + L_H1 + r * 64 + ((cb * 16) ^ ((r & 3) << 4)));
#pragma unroll
    for (int e = 0; e < 8; e++) h1v[cb * 8 + e] = (float)v[e];
  }
  const float* w3g = (const float*)(ws + SW_OFF);
  const float* w5g = (const float*)(ws + SW_OFF + 2816);
  const float* w7g = (const float*)(ws + SW_OFF + 4832);
  const float* b3g = (const float*)(ws + SW_OFF + 5792);
  const float* b5g = (const float*)(ws + SW_OFF + 5888);
  float* h3l = (float*)(sm + L_H3);
  float* h5l = (float*)(sm + L_H5);

#pragma unroll
  for (int i = 0; i < 6; i++) {
    int n = j + 4 * i;
    if (n < 22) {
      float s = b3g[n];
      const float4* wrow = (const float4*)(w3g + n * 32);
#pragma unroll
      for (int kk = 0; kk < 8; kk++) {
        float4 wv = wrow[kk];
        s += h1v[4 * kk] * wv.x + h1v[4 * kk + 1] * wv.y +
             h1v[4 * kk + 2] * wv.z + h1v[4 * kk + 3] * wv.w;
      }
      h3l[r * 25 + n] = fmaxf(s, 0.f);
    }
  }
  __syncthreads();
  float h3v[24];
#pragma unroll
  for (int k = 0; k < 24; k++) h3v[k] = (k < 22) ? h3l[r * 25 + k] : 0.f;
#pragma unroll
  for (int i = 0; i < 6; i++) {
    int n = j + 4 * i;
    if (n < 21) {
      float s = b5g[n];
      const float4* wrow = (const float4*)(w5g + n * 24);
#pragma unroll
      for (int kk = 0; kk < 6; kk++) {
        float4 wv = wrow[kk];
        s += h3v[4 * kk] * wv.x + h3v[4 * kk + 1] * wv.y +
             h3v[4 * kk + 2] * wv.z + h3v[4 * kk + 3] * wv.w;
      }
      h5l[r * 25 + n] = fmaxf(s, 0.f);
    }
  }
  __syncthreads();
  if (j == 0) {
    float h5v[24];
#pragma unroll
    for (int k = 0; k < 24; k++) h5v[k] = (k < 21) ? h5l[r * 25 + k] : 0.f;
    float lgt[10];
    float mx = -3.4e38f;
#pragma unroll
    for (int n = 0; n < 10; n++) {
      float s = 0.f;
      const float4* wrow = (const float4*)(w7g + n * 24);
#pragma unroll
      for (int kk = 0; kk < 6; kk++) {
        float4 wv = wrow[kk];
        s += h5v[4 * kk] * wv.x + h5v[4 * kk + 1] * wv.y +
             h5v[4 * kk + 2] * wv.z + h5v[4 * kk + 3] * wv.w;
      }
      lgt[n] = s;
      mx = fmaxf(mx, s);
    }
    float se = 0.f;
#pragma unroll
    for (int n = 0; n < 10; n++) se += __expf(lgt[n] - mx);
    const float lse = mx + __logf(se);
    float* os = (float*)(sm + L_OS);
#pragma unroll
    for (int n = 0; n < 10; n++) os[r * 10 + n] = lgt[n] - lse;
  }
  __syncthreads();
  {
    const float* os = (const float*)(sm + L_OS);
    float* ob = out + (size_t)blockIdx.x * 160;
    ob[l] = os[l];
    ob[64 + l] = os[64 + l];
    if (l < 32) ob[128 + l] = os[128 + l];
  }
}

extern "C" void kernel_launch(void* const* d_in, const int* in_sizes, int n_in,
                              void* d_out, int out_size, void* d_ws, size_t ws_size,
                              hipStream_t stream) {
  const float* x  = (const float*)d_in[0];
  const float* w0 = (const float*)d_in[1];
  const float* w1 = (const float*)d_in[2];
  const float* w3 = (const float*)d_in[3];
  const float* b3 = (const float*)d_in[4];
  const float* w5 = (const float*)d_in[5];
  const float* b5 = (const float*)d_in[6];
  const float* w7 = (const float*)d_in[7];
  float* out = (float*)d_out;
  char* ws = (char*)d_ws;

  const int prep_threads = W0F_UNITS + W1F_UNITS + 704 + 504 + 240 + 24 + 24;
  prep_weights<<<(prep_threads + 255) / 256, 256, 0, stream>>>(w0, w1, w3, b3,
                                                               w5, b5, w7, ws);
  fused_mlp<<<65536 / 16, 64, 0, stream>>>(x, ws, out);
}

// Round 10
// 60.991 us; speedup vs baseline: 1.5773x; 1.2254x over previous
//
#include <hip/hip_runtime.h>
#include <hip/hip_fp16.h>

typedef _Float16 half8 __attribute__((ext_vector_type(8)));
typedef __fp16 cvt2_t __attribute__((ext_vector_type(2)));
typedef float f32x4 __attribute__((ext_vector_type(4)));

// ---------------- workspace layout (bytes) ----------------
// W0F: fragment-ordered w0 fp16: uint4 index = t*1024 + kf2*512 + nf*64 + l
//      (t = k/64, kf2 = k32-half). Global k32-frag g -> t=g>>1, kf2=g&1.
#define W0F_UNITS (13 * 1024)
#define W1F_OFF   (W0F_UNITS * 16)
#define W1F_UNITS 512
#define SW_OFF    (W1F_OFF + W1F_UNITS * 16)

// ---------------- LDS (per 1-wave block, 32 rows) ----------------
#define L_H0   0        // [32 r][128 c] half, byte = r*256 + (2c ^ ((r&7)<<4))  (8192 B)
#define L_H1   8192     // [32 r][32 c]  half, byte = r*64  + (2c ^ ((r&3)<<4))  (2048 B)
#define L_H3   0        // [32][25] f32 (3200 B)  -- overlays H0
#define L_H5   3200     // [32][25] f32 (3200 B)
#define L_OS   6400     // [320] f32 out staging (1280 B)
#define LDS_SZ 10240

// ============ prep: rearrange weights into fragment order (unchanged) ============
__global__ void prep_weights(const float* __restrict__ w0,
                             const float* __restrict__ w1,
                             const float* __restrict__ w3,
                             const float* __restrict__ b3,
                             const float* __restrict__ w5,
                             const float* __restrict__ b5,
                             const float* __restrict__ w7,
                             char* __restrict__ ws) {
  int tid = blockIdx.x * 256 + threadIdx.x;
  if (tid < W0F_UNITS) {
    int t  = tid >> 10;
    int kf = (tid >> 9) & 1;
    int nf = (tid >> 6) & 7;
    int l  = tid & 63;
    int n  = nf * 16 + (l & 15);
    int k0 = t * 64 + kf * 32 + (l >> 4) * 8;
    alignas(16) __half h[8];
#pragma unroll
    for (int e = 0; e < 8; e++) {
      int k = k0 + e;
      h[e] = __float2half((n < 124 && k < 784) ? w0[n * 784 + k] : 0.f);
    }
    *(uint4*)(ws + tid * 16) = *(const uint4*)h;
    return;
  }
  int r = tid - W0F_UNITS;
  if (r < W1F_UNITS) {
    int kf = r >> 7;
    int nf = (r >> 6) & 1;
    int l  = r & 63;
    int n  = nf * 16 + (l & 15);
    int k0 = kf * 32 + (l >> 4) * 8;
    alignas(16) __half h[8];
#pragma unroll
    for (int e = 0; e < 8; e++) {
      int k = k0 + e;
      h[e] = __float2half((k < 124) ? w1[n * 124 + k] : 0.f);
    }
    *(uint4*)(ws + W1F_OFF + r * 16) = *(const uint4*)h;
    return;
  }
  r -= W1F_UNITS;
  float* sw = (float*)(ws + SW_OFF);
  if (r < 704) { sw[r] = w3[r]; return; }
  r -= 704;
  if (r < 504) {
    int n = r / 24, k = r % 24;
    sw[704 + r] = (k < 22) ? w5[n * 22 + k] : 0.f;
    return;
  }
  r -= 504;
  if (r < 240) {
    int n = r / 24, k = r % 24;
    sw[1208 + r] = (k < 21) ? w7[n * 21 + k] : 0.f;
    return;
  }
  r -= 240;
  if (r < 24) { sw[1448 + r] = (r < 22) ? b3[r] : 0.f; return; }
  r -= 24;
  if (r < 24) { sw[1472 + r] = (r < 21) ? b5[r] : 0.f; return; }
}

// ============ fused MLP: 1 wave = 32 rows, K-tile = 128 (512 B/row/visit) ============
__device__ __forceinline__ half8 cvt8(const f32x4& a, const f32x4& b) {
  cvt2_t p0 = __builtin_amdgcn_cvt_pkrtz(a[0], a[1]);
  cvt2_t p1 = __builtin_amdgcn_cvt_pkrtz(a[2], a[3]);
  cvt2_t p2 = __builtin_amdgcn_cvt_pkrtz(b[0], b[1]);
  cvt2_t p3 = __builtin_amdgcn_cvt_pkrtz(b[2], b[3]);
  uint4 u;
  u.x = __builtin_bit_cast(unsigned, p0);
  u.y = __builtin_bit_cast(unsigned, p1);
  u.z = __builtin_bit_cast(unsigned, p2);
  u.w = __builtin_bit_cast(unsigned, p3);
  return __builtin_bit_cast(half8, u);
}

__global__ __launch_bounds__(64, 2) void fused_mlp(
    const float* __restrict__ x, const char* __restrict__ ws,
    float* __restrict__ out) {
  __shared__ alignas(16) char sm[LDS_SZ];
  const int l  = threadIdx.x;
  const int lr = l & 15;
  const int lg = l >> 4;
  const size_t row0 = (size_t)blockIdx.x * 32;
  const uint4* wf = (const uint4*)ws;

  const float* xb0 = x + (row0 + lr) * 784;
  const float* xb1 = xb0 + 16 * 784;

  f32x4 acc[2][8];
#pragma unroll
  for (int mf = 0; mf < 2; mf++)
#pragma unroll
    for (int nf = 0; nf < 8; nf++) acc[mf][nf] = f32x4{0.f, 0.f, 0.f, 0.f};

  f32x4 xr[2][4][2];   // [mf][kf][h] fp32 staging of ONE tile (overwritten
                       // only after CVALL has converted it to afr)
  half8 afr[2][4];     // fp16 A-fragments of current tile
  half8 bfr[2][8];     // bf ping-pong by kf parity

  // x tile T: each row reads 512 B contiguous (4 kf x 128 B).
  // G=1 (tail T=6): only kf==0 && lg<2 valid (k 768..784), else zero.
#define XL(T, G)                                                               \
  {                                                                            \
    _Pragma("unroll") for (int mf = 0; mf < 2; mf++)                           \
        _Pragma("unroll") for (int kf = 0; kf < 4; kf++)                       \
            _Pragma("unroll") for (int h = 0; h < 2; h++) {                    \
      const float* p =                                                         \
          (mf ? xb1 : xb0) + (T) * 128 + kf * 32 + lg * 8 + h * 4;             \
      if (!(G) || (kf == 0 && lg < 2))                                         \
        xr[mf][kf][h] = *(const f32x4*)p;                                      \
      else                                                                     \
        xr[mf][kf][h] = f32x4{0.f, 0.f, 0.f, 0.f};                             \
    }                                                                          \
  }

  // convert ALL 4 k-frags of the staged tile to fp16 regs; xr is then dead
#define CVALL()                                                                \
  {                                                                            \
    _Pragma("unroll") for (int mf = 0; mf < 2; mf++)                           \
        _Pragma("unroll") for (int kf = 0; kf < 4; kf++)                       \
            afr[mf][kf] = cvt8(xr[mf][kf][0], xr[mf][kf][1]);                  \
  }

#define BFL(P, G)                                                              \
  {                                                                            \
    _Pragma("unroll") for (int nf = 0; nf < 8; nf++)                           \
      bfr[P][nf] = __builtin_bit_cast(                                         \
          half8, wf[((G) >> 1) * 1024 + ((G) & 1) * 512 + nf * 64 + l]);       \
  }

#define MFK(KF, P)                                                             \
  {                                                                            \
    _Pragma("unroll") for (int nf = 0; nf < 8; nf++) {                         \
      acc[0][nf] = __builtin_amdgcn_mfma_f32_16x16x32_f16(                     \
          afr[0][KF], bfr[P][nf], acc[0][nf], 0, 0, 0);                        \
      acc[1][nf] = __builtin_amdgcn_mfma_f32_16x16x32_f16(                     \
          afr[1][KF], bfr[P][nf], acc[1][nf], 0, 0, 0);                        \
    }                                                                          \
  }

  // body T: cvt tile T -> afr, THEN prefetch x(T+1) into xr (regs dead),
  // then 4x MFMA interleaved with bf refills.
#define BODY(T, GN)                                                            \
  {                                                                            \
    CVALL()                                                                    \
    XL((T) + 1, GN)                                                            \
    MFK(0, 0)                                                                  \
    BFL(0, (T) * 4 + 2)                                                        \
    MFK(1, 1)                                                                  \
    BFL(1, (T) * 4 + 3)                                                        \
    MFK(2, 0)                                                                  \
    BFL(0, ((T) + 1) * 4 + 0)                                                  \
    MFK(3, 1)                                                                  \
    BFL(1, ((T) + 1) * 4 + 1)                                                  \
  }

  // prologue: x(0), bf g0 (par0), g1 (par1)
  XL(0, 0)
  BFL(0, 0)
  BFL(1, 1)

  BODY(0, 0)
  BODY(1, 0)
  BODY(2, 0)
  BODY(3, 0)
  BODY(4, 0)
  BODY(5, 1)    // prefetches tail tile 6 (partial) and bf g24/g25
  // tail: g24 (k 768..800; x/w zero-padded beyond 784)
  CVALL()
  MFK(0, 0)

  // issue w1 fragment loads early (consumed in phase 2)
  half8 b1[4][2];
  {
    const uint4* w1f = (const uint4*)(ws + W1F_OFF);
#pragma unroll
    for (int kf = 0; kf < 4; kf++)
#pragma unroll
      for (int nf = 0; nf < 2; nf++)
        b1[kf][nf] = __builtin_bit_cast(half8, w1f[kf * 128 + nf * 64 + l]);
  }

  // ---- phase 1: h0 -> LDS fp16, swizzled ----
#pragma unroll
  for (int mf = 0; mf < 2; mf++)
#pragma unroll
    for (int nf = 0; nf < 8; nf++)
#pragma unroll
      for (int q = 0; q < 4; q++) {
        int rr = mf * 16 + lg * 4 + q;
        int cc = nf * 16 + lr;
        *(__half*)(sm + L_H0 + rr * 256 + ((2 * cc) ^ ((rr & 7) << 4))) =
            __float2half(acc[mf][nf][q]);
      }
  __syncthreads();

  // ---- phase 2: layer 1 (N=32, K=128pad) + relu -> h1 ----
  f32x4 acc1[2][2];
#pragma unroll
  for (int mf = 0; mf < 2; mf++) {
    acc1[mf][0] = f32x4{0.f, 0.f, 0.f, 0.f};
    acc1[mf][1] = f32x4{0.f, 0.f, 0.f, 0.f};
  }
#pragma unroll
  for (int kf = 0; kf < 4; kf++) {
    half8 a1[2];
#pragma unroll
    for (int mf = 0; mf < 2; mf++) {
      int rr = mf * 16 + lr;
      int cb = kf * 64 + lg * 16;
      a1[mf] = *(const half8*)(sm + L_H0 + rr * 256 + (cb ^ ((rr & 7) << 4)));
    }
#pragma unroll
    for (int mf = 0; mf < 2; mf++)
#pragma unroll
      for (int nf = 0; nf < 2; nf++)
        acc1[mf][nf] = __builtin_amdgcn_mfma_f32_16x16x32_f16(
            a1[mf], b1[kf][nf], acc1[mf][nf], 0, 0, 0);
  }
#pragma unroll
  for (int mf = 0; mf < 2; mf++)
#pragma unroll
    for (int nf = 0; nf < 2; nf++)
#pragma unroll
      for (int q = 0; q < 4; q++) {
        int rr = mf * 16 + lg * 4 + q;
        int cc = nf * 16 + lr;
        float v = fmaxf(acc1[mf][nf][q], 0.f);
        *(__half*)(sm + L_H1 + rr * 64 + ((2 * cc) ^ ((rr & 3) << 4))) =
            __float2half(v);
      }
  __syncthreads();

  // ---- phase 3: layers 3,5,7 + log_softmax (fp32, 2 lanes per row) ----
  const int r = l & 31;
  const int j = l >> 5;
  float h1v[32];
#pragma unroll
  for (int cb = 0; cb < 4; cb++) {
    half8 v = *(const half8*)(sm + L_H1 + r * 64 + ((cb * 16) ^ ((r & 3) << 4)));
#pragma unroll
    for (int e = 0; e < 8; e++) h1v[cb * 8 + e] = (float)v[e];
  }
  const float* w3g = (const float*)(ws + SW_OFF);
  const float* w5g = (const float*)(ws + SW_OFF + 2816);
  const float* w7g = (const float*)(ws + SW_OFF + 4832);
  const float* b3g = (const float*)(ws + SW_OFF + 5792);
  const float* b5g = (const float*)(ws + SW_OFF + 5888);
  float* h3l = (float*)(sm + L_H3);
  float* h5l = (float*)(sm + L_H5);

#pragma unroll
  for (int i = 0; i < 11; i++) {
    int n = j + 2 * i;
    float s = b3g[n];
    const float4* wrow = (const float4*)(w3g + n * 32);
#pragma unroll
    for (int kk = 0; kk < 8; kk++) {
      float4 wv = wrow[kk];
      s += h1v[4 * kk] * wv.x + h1v[4 * kk + 1] * wv.y +
           h1v[4 * kk + 2] * wv.z + h1v[4 * kk + 3] * wv.w;
    }
    h3l[r * 25 + n] = fmaxf(s, 0.f);
  }
  __syncthreads();
  float h3v[24];
#pragma unroll
  for (int k = 0; k < 24; k++) h3v[k] = (k < 22) ? h3l[r * 25 + k] : 0.f;
#pragma unroll
  for (int i = 0; i < 11; i++) {
    int n = j + 2 * i;
    if (n < 21) {
      float s = b5g[n];
      const float4* wrow = (const float4*)(w5g + n * 24);
#pragma unroll
      for (int kk = 0; kk < 6; kk++) {
        float4 wv = wrow[kk];
        s += h3v[4 * kk] * wv.x + h3v[4 * kk + 1] * wv.y +
             h3v[4 * kk + 2] * wv.z + h3v[4 * kk + 3] * wv.w;
      }
      h5l[r * 25 + n] = fmaxf(s, 0.f);
    }
  }
  __syncthreads();
  if (j == 0) {
    float h5v[24];
#pragma unroll
    for (int k = 0; k < 24; k++) h5v[k] = (k < 21) ? h5l[r * 25 + k] : 0.f;
    float lgt[10];
    float mx = -3.4e38f;
#pragma unroll
    for (int n = 0; n < 10; n++) {
      float s = 0.f;
      const float4* wrow = (const float4*)(w7g + n * 24);
#pragma unroll
      for (int kk = 0; kk < 6; kk++) {
        float4 wv = wrow[kk];
        s += h5v[4 * kk] * wv.x + h5v[4 * kk + 1] * wv.y +
             h5v[4 * kk + 2] * wv.z + h5v[4 * kk + 3] * wv.w;
      }
      lgt[n] = s;
      mx = fmaxf(mx, s);
    }
    float se = 0.f;
#pragma unroll
    for (int n = 0; n < 10; n++) se += __expf(lgt[n] - mx);
    const float lse = mx + __logf(se);
    float* os = (float*)(sm + L_OS);
#pragma unroll
    for (int n = 0; n < 10; n++) os[r * 10 + n] = lgt[n] - lse;
  }
  __syncthreads();
  {
    const float* os = (const float*)(sm + L_OS);
#pragma unroll
    for (int i = 0; i < 5; i++) out[row0 * 10 + i * 64 + l] = os[i * 64 + l];
  }
}

extern "C" void kernel_launch(void* const* d_in, const int* in_sizes, int n_in,
                              void* d_out, int out_size, void* d_ws, size_t ws_size,
                              hipStream_t stream) {
  const float* x  = (const float*)d_in[0];
  const float* w0 = (const float*)d_in[1];
  const float* w1 = (const float*)d_in[2];
  const float* w3 = (const float*)d_in[3];
  const float* b3 = (const float*)d_in[4];
  const float* w5 = (const float*)d_in[5];
  const float* b5 = (const float*)d_in[6];
  const float* w7 = (const float*)d_in[7];
  float* out = (float*)d_out;
  char* ws = (char*)d_ws;

  const int prep_threads = W0F_UNITS + W1F_UNITS + 704 + 504 + 240 + 24 + 24;
  prep_weights<<<(prep_threads + 255) / 256, 256, 0, stream>>>(w0, w1, w3, b3,
                                                               w5, b5, w7, ws);
  fused_mlp<<<65536 / 32, 64, 0, stream>>>(x, ws, out);
}

// Round 11
// 59.046 us; speedup vs baseline: 1.6293x; 1.0329x over previous
//
#include <hip/hip_runtime.h>
#include <hip/hip_fp16.h>

typedef _Float16 half8 __attribute__((ext_vector_type(8)));
typedef __fp16 cvt2_t __attribute__((ext_vector_type(2)));
typedef float f32x4 __attribute__((ext_vector_type(4)));

// ---------------- workspace layout (bytes) ----------------
#define W0F_UNITS (13 * 1024)
#define W1F_OFF   (W0F_UNITS * 16)
#define W1F_UNITS 512
#define SW_OFF    (W1F_OFF + W1F_UNITS * 16)

// ---------------- LDS (per 1-wave block, 32 rows) ----------------
// XT0/XT1: [32 r][64 k] fp16 swizzled, byte = r*128 + ((8c4)^((r&7)<<4))
#define L_XT0  0        // 4096
#define L_XT1  4096     // 4096
#define L_H0   0        // [32][128] half (8192) -- overlays XT after main loop
#define L_H1   8192     // [32][32] half (2048)
#define L_H3   0        // [32][25] f32 (3200) -- overlays H0
#define L_H5   3200
#define L_OS   6400
#define LDS_SZ 10240

// ============ prep: rearrange weights into fragment order (unchanged) ============
__global__ void prep_weights(const float* __restrict__ w0,
                             const float* __restrict__ w1,
                             const float* __restrict__ w3,
                             const float* __restrict__ b3,
                             const float* __restrict__ w5,
                             const float* __restrict__ b5,
                             const float* __restrict__ w7,
                             char* __restrict__ ws) {
  int tid = blockIdx.x * 256 + threadIdx.x;
  if (tid < W0F_UNITS) {
    int t  = tid >> 10;
    int kf = (tid >> 9) & 1;
    int nf = (tid >> 6) & 7;
    int l  = tid & 63;
    int n  = nf * 16 + (l & 15);
    int k0 = t * 64 + kf * 32 + (l >> 4) * 8;
    alignas(16) __half h[8];
#pragma unroll
    for (int e = 0; e < 8; e++) {
      int k = k0 + e;
      h[e] = __float2half((n < 124 && k < 784) ? w0[n * 784 + k] : 0.f);
    }
    *(uint4*)(ws + tid * 16) = *(const uint4*)h;
    return;
  }
  int r = tid - W0F_UNITS;
  if (r < W1F_UNITS) {
    int kf = r >> 7;
    int nf = (r >> 6) & 1;
    int l  = r & 63;
    int n  = nf * 16 + (l & 15);
    int k0 = kf * 32 + (l >> 4) * 8;
    alignas(16) __half h[8];
#pragma unroll
    for (int e = 0; e < 8; e++) {
      int k = k0 + e;
      h[e] = __float2half((k < 124) ? w1[n * 124 + k] : 0.f);
    }
    *(uint4*)(ws + W1F_OFF + r * 16) = *(const uint4*)h;
    return;
  }
  r -= W1F_UNITS;
  float* sw = (float*)(ws + SW_OFF);
  if (r < 704) { sw[r] = w3[r]; return; }
  r -= 704;
  if (r < 504) {
    int n = r / 24, k = r % 24;
    sw[704 + r] = (k < 22) ? w5[n * 22 + k] : 0.f;
    return;
  }
  r -= 504;
  if (r < 240) {
    int n = r / 24, k = r % 24;
    sw[1208 + r] = (k < 21) ? w7[n * 21 + k] : 0.f;
    return;
  }
  r -= 240;
  if (r < 24) { sw[1448 + r] = (r < 22) ? b3[r] : 0.f; return; }
  r -= 24;
  if (r < 24) { sw[1472 + r] = (r < 21) ? b5[r] : 0.f; return; }
}

// ============ fused MLP: 1 wave = 32 rows, full-line x reads + LDS redistrib ====
__global__ __launch_bounds__(64, 2) void fused_mlp(
    const float* __restrict__ x, const char* __restrict__ ws,
    float* __restrict__ out) {
  __shared__ alignas(16) char sm[LDS_SZ];
  const int l  = threadIdx.x;
  const int lr = l & 15;
  const int lg = l >> 4;
  const size_t row0 = (size_t)blockIdx.x * 32;
  const uint4* wf = (const uint4*)ws;

  f32x4 acc[2][8];
#pragma unroll
  for (int mf = 0; mf < 2; mf++)
#pragma unroll
    for (int nf = 0; nf < 8; nf++) acc[mf][nf] = f32x4{0.f, 0.f, 0.f, 0.f};

  f32x4 xr[8];       // one staged tile: instr i = rows 4i..4i+3, 256 B/row
  half8 bfr[2][8];   // bf ping-pong by kf parity
  half8 af[2][2];    // A-fragments of current tile

  // FULL-LINE load of tile T: instr i covers 4 consecutive rows x 256 B
  // (every request is a complete 128 B line). G=1: tail tile 12, only
  // floats 0..15 of the tile valid ((l&15)<4).
#define XL(T, G)                                                               \
  {                                                                            \
    _Pragma("unroll") for (int i = 0; i < 8; i++) {                            \
      const int rr = 4 * i + lg;                                               \
      const float* p = x + (row0 + rr) * 784 + (T) * 64 + lr * 4;              \
      xr[i] = (!(G) || lr < 4) ? *(const f32x4*)p : f32x4{0.f, 0.f, 0.f, 0.f}; \
    }                                                                          \
  }

  // cvt fp32->fp16 + swizzled LDS store (lane: row 4i+lg, k-chunk lr*4)
#define XST(BUF)                                                               \
  {                                                                            \
    _Pragma("unroll") for (int i = 0; i < 8; i++) {                            \
      const int rr = 4 * i + lg;                                               \
      cvt2_t q0 = __builtin_amdgcn_cvt_pkrtz(xr[i][0], xr[i][1]);              \
      cvt2_t q1 = __builtin_amdgcn_cvt_pkrtz(xr[i][2], xr[i][3]);              \
      uint2 u;                                                                 \
      u.x = __builtin_bit_cast(unsigned, q0);                                  \
      u.y = __builtin_bit_cast(unsigned, q1);                                  \
      *(uint2*)(sm + (BUF) + rr * 128 + ((8 * lr) ^ ((rr & 7) << 4))) = u;     \
    }                                                                          \
  }

  // read MFMA A-fragments of the tile from LDS
#define ARD(BUF)                                                               \
  {                                                                            \
    _Pragma("unroll") for (int mf = 0; mf < 2; mf++)                           \
        _Pragma("unroll") for (int kf = 0; kf < 2; kf++) {                     \
      const int rr = lr + mf * 16;                                             \
      af[mf][kf] = *(const half8*)(                                            \
          sm + (BUF) + rr * 128 + ((kf * 64 + lg * 16) ^ ((rr & 7) << 4)));    \
    }                                                                          \
  }

#define BFL(P, G)                                                              \
  {                                                                            \
    _Pragma("unroll") for (int nf = 0; nf < 8; nf++)                           \
      bfr[P][nf] = __builtin_bit_cast(                                         \
          half8, wf[((G) >> 1) * 1024 + ((G) & 1) * 512 + nf * 64 + l]);       \
  }

#define MFK(KF, P)                                                             \
  {                                                                            \
    _Pragma("unroll") for (int nf = 0; nf < 8; nf++) {                         \
      acc[0][nf] = __builtin_amdgcn_mfma_f32_16x16x32_f16(                     \
          af[0][KF], bfr[P][nf], acc[0][nf], 0, 0, 0);                         \
      acc[1][nf] = __builtin_amdgcn_mfma_f32_16x16x32_f16(                     \
          af[1][KF], bfr[P][nf], acc[1][nf], 0, 0, 0);                         \
    }                                                                          \
  }

  // body T: frags from LDS[T&1], MFMA, store x(T+1) regs->LDS[(T+1)&1],
  // issue x(T+2). FIFO: bf(T) issued before x(T+1) -> MFK's bf-wait keeps
  // the x prefetch; XST waits x(T+1) with one full body of cover.
#define BODY(T, BUFC, BUFN, DO_STAGE, DO_LOAD, GNEXT)                          \
  {                                                                            \
    ARD(BUFC)                                                                  \
    MFK(0, 0)                                                                  \
    if (DO_STAGE) BFL(0, 2 * (T) + 2)                                          \
    MFK(1, 1)                                                                  \
    if (DO_STAGE) BFL(1, 2 * (T) + 3)                                          \
    if (DO_STAGE) XST(BUFN)                                                    \
    if (DO_LOAD) XL((T) + 2, GNEXT)                                            \
  }

  // prologue: x(0) -> LDS0; bf g0/g1; x(1) in regs
  XL(0, 0)
  BFL(0, 0)
  BFL(1, 1)
  XST(L_XT0)
  XL(1, 0)

  BODY(0,  L_XT0, L_XT1, 1, 1, 0)
  BODY(1,  L_XT1, L_XT0, 1, 1, 0)
  BODY(2,  L_XT0, L_XT1, 1, 1, 0)
  BODY(3,  L_XT1, L_XT0, 1, 1, 0)
  BODY(4,  L_XT0, L_XT1, 1, 1, 0)
  BODY(5,  L_XT1, L_XT0, 1, 1, 0)
  BODY(6,  L_XT0, L_XT1, 1, 1, 0)
  BODY(7,  L_XT1, L_XT0, 1, 1, 0)
  BODY(8,  L_XT0, L_XT1, 1, 1, 0)
  BODY(9,  L_XT1, L_XT0, 1, 1, 0)
  BODY(10, L_XT0, L_XT1, 1, 1, 1)   // loads x(12) partial
  BODY(11, L_XT1, L_XT0, 1, 0, 0)   // stores x(12); bf g24/g25; no x(13)
  BODY(12, L_XT0, L_XT1, 0, 0, 0)   // final tile, no staging

  // issue w1 fragment loads early (consumed in phase 2)
  half8 b1[4][2];
  {
    const uint4* w1f = (const uint4*)(ws + W1F_OFF);
#pragma unroll
    for (int kf = 0; kf < 4; kf++)
#pragma unroll
      for (int nf = 0; nf < 2; nf++)
        b1[kf][nf] = __builtin_bit_cast(half8, w1f[kf * 128 + nf * 64 + l]);
  }

  // ---- phase 1: h0 -> LDS fp16, swizzled (overlays XT) ----
#pragma unroll
  for (int mf = 0; mf < 2; mf++)
#pragma unroll
    for (int nf = 0; nf < 8; nf++)
#pragma unroll
      for (int q = 0; q < 4; q++) {
        int rr = mf * 16 + lg * 4 + q;
        int cc = nf * 16 + lr;
        *(__half*)(sm + L_H0 + rr * 256 + ((2 * cc) ^ ((rr & 7) << 4))) =
            __float2half(acc[mf][nf][q]);
      }
  __syncthreads();

  // ---- phase 2: layer 1 (N=32, K=128pad) + relu -> h1 ----
  f32x4 acc1[2][2];
#pragma unroll
  for (int mf = 0; mf < 2; mf++) {
    acc1[mf][0] = f32x4{0.f, 0.f, 0.f, 0.f};
    acc1[mf][1] = f32x4{0.f, 0.f, 0.f, 0.f};
  }
#pragma unroll
  for (int kf = 0; kf < 4; kf++) {
    half8 a1[2];
#pragma unroll
    for (int mf = 0; mf < 2; mf++) {
      int rr = mf * 16 + lr;
      int cb = kf * 64 + lg * 16;
      a1[mf] = *(const half8*)(sm + L_H0 + rr * 256 + (cb ^ ((rr & 7) << 4)));
    }
#pragma unroll
    for (int mf = 0; mf < 2; mf++)
#pragma unroll
      for (int nf = 0; nf < 2; nf++)
        acc1[mf][nf] = __builtin_amdgcn_mfma_f32_16x16x32_f16(
            a1[mf], b1[kf][nf], acc1[mf][nf], 0, 0, 0);
  }
#pragma unroll
  for (int mf = 0; mf < 2; mf++)
#pragma unroll
    for (int nf = 0; nf < 2; nf++)
#pragma unroll
      for (int q = 0; q < 4; q++) {
        int rr = mf * 16 + lg * 4 + q;
        int cc = nf * 16 + lr;
        float v = fmaxf(acc1[mf][nf][q], 0.f);
        *(__half*)(sm + L_H1 + rr * 64 + ((2 * cc) ^ ((rr & 3) << 4))) =
            __float2half(v);
      }
  __syncthreads();

  // ---- phase 3: layers 3,5,7 + log_softmax (fp32, 2 lanes per row) ----
  const int r = l & 31;
  const int j = l >> 5;
  float h1v[32];
#pragma unroll
  for (int cb = 0; cb < 4; cb++) {
    half8 v = *(const half8*)(sm + L_H1 + r * 64 + ((cb * 16) ^ ((r & 3) << 4)));
#pragma unroll
    for (int e = 0; e < 8; e++) h1v[cb * 8 + e] = (float)v[e];
  }
  const float* w3g = (const float*)(ws + SW_OFF);
  const float* w5g = (const float*)(ws + SW_OFF + 2816);
  const float* w7g = (const float*)(ws + SW_OFF + 4832);
  const float* b3g = (const float*)(ws + SW_OFF + 5792);
  const float* b5g = (const float*)(ws + SW_OFF + 5888);
  float* h3l = (float*)(sm + L_H3);
  float* h5l = (float*)(sm + L_H5);

#pragma unroll
  for (int i = 0; i < 11; i++) {
    int n = j + 2 * i;
    float s = b3g[n];
    const float4* wrow = (const float4*)(w3g + n * 32);
#pragma unroll
    for (int kk = 0; kk < 8; kk++) {
      float4 wv = wrow[kk];
      s += h1v[4 * kk] * wv.x + h1v[4 * kk + 1] * wv.y +
           h1v[4 * kk + 2] * wv.z + h1v[4 * kk + 3] * wv.w;
    }
    h3l[r * 25 + n] = fmaxf(s, 0.f);
  }
  __syncthreads();
  float h3v[24];
#pragma unroll
  for (int k = 0; k < 24; k++) h3v[k] = (k < 22) ? h3l[r * 25 + k] : 0.f;
#pragma unroll
  for (int i = 0; i < 11; i++) {
    int n = j + 2 * i;
    if (n < 21) {
      float s = b5g[n];
      const float4* wrow = (const float4*)(w5g + n * 24);
#pragma unroll
      for (int kk = 0; kk < 6; kk++) {
        float4 wv = wrow[kk];
        s += h3v[4 * kk] * wv.x + h3v[4 * kk + 1] * wv.y +
             h3v[4 * kk + 2] * wv.z + h3v[4 * kk + 3] * wv.w;
      }
      h5l[r * 25 + n] = fmaxf(s, 0.f);
    }
  }
  __syncthreads();
  if (j == 0) {
    float h5v[24];
#pragma unroll
    for (int k = 0; k < 24; k++) h5v[k] = (k < 21) ? h5l[r * 25 + k] : 0.f;
    float lgt[10];
    float mx = -3.4e38f;
#pragma unroll
    for (int n = 0; n < 10; n++) {
      float s = 0.f;
      const float4* wrow = (const float4*)(w7g + n * 24);
#pragma unroll
      for (int kk = 0; kk < 6; kk++) {
        float4 wv = wrow[kk];
        s += h5v[4 * kk] * wv.x + h5v[4 * kk + 1] * wv.y +
             h5v[4 * kk + 2] * wv.z + h5v[4 * kk + 3] * wv.w;
      }
      lgt[n] = s;
      mx = fmaxf(mx, s);
    }
    float se = 0.f;
#pragma unroll
    for (int n = 0; n < 10; n++) se += __expf(lgt[n] - mx);
    const float lse = mx + __logf(se);
    float* os = (float*)(sm + L_OS);
#pragma unroll
    for (int n = 0; n < 10; n++) os[r * 10 + n] = lgt[n] - lse;
  }
  __syncthreads();
  {
    const float* os = (const float*)(sm + L_OS);
#pragma unroll
    for (int i = 0; i < 5; i++) out[row0 * 10 + i * 64 + l] = os[i * 64 + l];
  }
}

extern "C" void kernel_launch(void* const* d_in, const int* in_sizes, int n_in,
                              void* d_out, int out_size, void* d_ws, size_t ws_size,
                              hipStream_t stream) {
  const float* x  = (const float*)d_in[0];
  const float* w0 = (const float*)d_in[1];
  const float* w1 = (const float*)d_in[2];
  const float* w3 = (const float*)d_in[3];
  const float* b3 = (const float*)d_in[4];
  const float* w5 = (const float*)d_in[5];
  const float* b5 = (const float*)d_in[6];
  const float* w7 = (const float*)d_in[7];
  float* out = (float*)d_out;
  char* ws = (char*)d_ws;

  const int prep_threads = W0F_UNITS + W1F_UNITS + 704 + 504 + 240 + 24 + 24;
  prep_weights<<<(prep_threads + 255) / 256, 256, 0, stream>>>(w0, w1, w3, b3,
                                                               w5, b5, w7, ws);
  fused_mlp<<<65536 / 32, 64, 0, stream>>>(x, ws, out);
}